// Round 3
// baseline (340.344 us; speedup 1.0000x reference)
//
#include <hip/hip_runtime.h>
#include <cstdint>

typedef _Float16 f16x8 __attribute__((ext_vector_type(8)));
typedef _Float16 f16x4 __attribute__((ext_vector_type(4)));
typedef float    f32x4 __attribute__((ext_vector_type(4)));

#define AS1 __attribute__((address_space(1)))
#define AS3 __attribute__((address_space(3)))

__device__ __forceinline__ void load16_lds(const void* g, void* l) {
  __builtin_amdgcn_global_load_lds((AS1 void*)g, (AS3 void*)l, 16, 0, 0);
}

// ---------------- fused fp32 -> fp16 convert for all 5 inputs ----------------
// grid = 12288 blocks x 256 = 3,145,728 float4 slots:
//   [0, 2097152)        x  -> xh
//   [2097152, 2359296)  Wq -> Wcat
//   [2359296, 2621440)  Wk -> Wcat+1M halves
//   [2621440, 2883584)  Wv -> Wcat+2M halves
//   [2883584, 3145728)  Wo -> Woh
__global__ __launch_bounds__(256) void cvt_all(
    const float* __restrict__ x, const float* __restrict__ wq,
    const float* __restrict__ wk, const float* __restrict__ wv,
    const float* __restrict__ wo,
    _Float16* __restrict__ xh, _Float16* __restrict__ wcat,
    _Float16* __restrict__ woh) {
  long long g = (long long)blockIdx.x * 256 + threadIdx.x;
  const float* in; _Float16* out; long long idx;
  if (g < 2097152)      { in = x;  out = xh;             idx = g; }
  else if (g < 2359296) { in = wq; out = wcat;           idx = g - 2097152; }
  else if (g < 2621440) { in = wk; out = wcat + 1048576; idx = g - 2359296; }
  else if (g < 2883584) { in = wv; out = wcat + 2097152; idx = g - 2621440; }
  else                  { in = wo; out = woh;            idx = g - 2883584; }
  float4 v = ((const float4*)in)[idx];
  f16x4 o;
  o[0] = (_Float16)v.x; o[1] = (_Float16)v.y; o[2] = (_Float16)v.z; o[3] = (_Float16)v.w;
  ((f16x4*)out)[idx] = o;
}

// ---------------- causal softmax (vectorized) ----------------
// One block per row (g = b*2048 + i). float4 reads of the fp32 prefix [0..i],
// f16x4 writes of P into the UPPER HALF (byte offset +4096) of the same row,
// zero-padded up to the row's 128-tile edge.
__global__ __launch_bounds__(256) void softmax_causal(float* __restrict__ Sbuf) {
  int g = blockIdx.x;
  int row = g & 2047;
  float* srow = Sbuf + (size_t)g * 2048;
  _Float16* prow = (_Float16*)srow + 2048;
  int L = row + 1;
  int L4 = L & ~3;
  int Lp = ((row >> 7) + 1) << 7;
  int t = threadIdx.x;
  int lane = t & 63, w = t >> 6;

  const float4* s4 = (const float4*)srow;
  float4 v[2];
  int cnt = 0;
  float mx = -3.0e38f;
  for (int j4 = t; j4 * 4 < L4; j4 += 256) {
    float4 q = s4[j4];
    v[cnt++] = q;
    mx = fmaxf(mx, fmaxf(fmaxf(q.x, q.y), fmaxf(q.z, q.w)));
  }
  int jt = L4 + t;
  float tailv = 0.f;
  bool hasTail = (jt < L);
  if (hasTail) { tailv = srow[jt]; mx = fmaxf(mx, tailv); }

  __shared__ float sm[8];
  #pragma unroll
  for (int off = 32; off > 0; off >>= 1) mx = fmaxf(mx, __shfl_down(mx, off));
  if (lane == 0) sm[w] = mx;
  __syncthreads();
  if (t == 0) { float m2 = sm[0]; for (int q = 1; q < 4; q++) m2 = fmaxf(m2, sm[q]); sm[0] = m2; }
  __syncthreads();
  mx = sm[0];

  float sum = 0.f;
  for (int c = 0; c < cnt; c++) {
    v[c].x = __expf(v[c].x - mx); v[c].y = __expf(v[c].y - mx);
    v[c].z = __expf(v[c].z - mx); v[c].w = __expf(v[c].w - mx);
    sum += (v[c].x + v[c].y) + (v[c].z + v[c].w);
  }
  float te = 0.f;
  if (hasTail) { te = __expf(tailv - mx); sum += te; }
  #pragma unroll
  for (int off = 32; off > 0; off >>= 1) sum += __shfl_down(sum, off);
  if (lane == 0) sm[4 + w] = sum;
  __syncthreads();
  if (t == 0) sm[4] = 1.0f / (sm[4] + sm[5] + sm[6] + sm[7]);
  __syncthreads();
  float inv = sm[4];

  f16x4* p4 = (f16x4*)prow;
  cnt = 0;
  for (int j4 = t; j4 * 4 < L4; j4 += 256) {
    float4 q = v[cnt++];
    f16x4 o;
    o[0] = (_Float16)(q.x * inv); o[1] = (_Float16)(q.y * inv);
    o[2] = (_Float16)(q.z * inv); o[3] = (_Float16)(q.w * inv);
    p4[j4] = o;
  }
  if (hasTail) prow[jt] = (_Float16)(te * inv);
  for (int j = L + t; j < Lp; j += 256) prow[j] = (_Float16)0.0f;
}

// ---------------- generic A * B^T GEMM, m97 structure ----------------
// OUTMODE: 2 = fp32 normal, 3 = fp32 + bias.
template <int OUTMODE, bool CAUSAL_SKIP>
__global__ __launch_bounds__(256) void gemm_bt(
    const _Float16* __restrict__ A, const _Float16* __restrict__ B,
    void* __restrict__ Cv, const float* __restrict__ bias,
    int K, int lda, int ldb, int ldc,
    long long aBatch, long long bBatch, long long cBatch) {
  int bx = blockIdx.x, by = blockIdx.y, bz = blockIdx.z;
  if (CAUSAL_SKIP && bx > by) return;
  const _Float16* Ab = A + (long long)bz * aBatch + (long long)by * 128 * lda;
  const _Float16* Bb = B + (long long)bz * bBatch + (long long)bx * 128 * ldb;

  __shared__ _Float16 lA[128 * 32];
  __shared__ _Float16 lB[128 * 32];

  int tid = threadIdx.x;
  int r0 = tid >> 2;
  int c0 = (tid & 3) * 8;
  const _Float16* ga0 = Ab + (long long)r0 * lda + c0;
  const _Float16* ga1 = Ab + (long long)(r0 + 64) * lda + c0;
  const _Float16* gb0 = Bb + (long long)r0 * ldb + c0;
  const _Float16* gb1 = Bb + (long long)(r0 + 64) * ldb + c0;
  _Float16* la0 = lA + tid * 8;
  _Float16* la1 = lA + 2048 + tid * 8;
  _Float16* lb0 = lB + tid * 8;
  _Float16* lb1 = lB + 2048 + tid * 8;

  f32x4 acc[4][4] = {};
  int lane = tid & 63;
  int wv = tid >> 6;
  int wm = (wv & 1) * 64, wn = (wv >> 1) * 64;
  int l16 = lane & 15, quad = lane >> 4;
  const _Float16* raBase = lA + (wm + l16) * 32 + quad * 8;
  const _Float16* rbBase = lB + (wn + l16) * 32 + quad * 8;

  for (int kb = 0; kb < K; kb += 32) {
    __syncthreads();
    load16_lds(ga0, la0);
    load16_lds(ga1, la1);
    load16_lds(gb0, lb0);
    load16_lds(gb1, lb1);
    ga0 += 32; ga1 += 32; gb0 += 32; gb1 += 32;
    __syncthreads();
    f16x8 af[4], bfr[4];
    #pragma unroll
    for (int i = 0; i < 4; i++) af[i] = *(const f16x8*)(raBase + i * 512);
    #pragma unroll
    for (int j = 0; j < 4; j++) bfr[j] = *(const f16x8*)(rbBase + j * 512);
    #pragma unroll
    for (int i = 0; i < 4; i++)
      #pragma unroll
      for (int j = 0; j < 4; j++)
        acc[i][j] = __builtin_amdgcn_mfma_f32_16x16x32_f16(af[i], bfr[j], acc[i][j], 0, 0, 0);
  }

  int m0 = by * 128 + wm + quad * 4;
  int n0 = bx * 128 + wn + l16;

  if (OUTMODE == 2) {
    float* C = (float*)Cv + (long long)bz * cBatch;
    #pragma unroll
    for (int i = 0; i < 4; i++)
      #pragma unroll
      for (int j = 0; j < 4; j++)
        #pragma unroll
        for (int r = 0; r < 4; r++)
          C[(long long)(m0 + i * 16 + r) * ldc + (n0 + j * 16)] = acc[i][j][r];
  } else {
    float* C = (float*)Cv + (long long)bz * cBatch;
    #pragma unroll
    for (int j = 0; j < 4; j++) {
      float bj = bias[n0 + j * 16];
      #pragma unroll
      for (int i = 0; i < 4; i++)
        #pragma unroll
        for (int r = 0; r < 4; r++)
          C[(long long)(m0 + i * 16 + r) * ldc + (n0 + j * 16)] = acc[i][j][r] + bj;
    }
  }
}

// ---------------- fused QKV projection ----------------
// A = xh [8192][1024], B = Wcat [3072][1024] (Wq|Wk|Wv rows).
// grid (24, 64): bx<8 -> Qh, bx<16 -> Kh, else Vt transposed [b][d][s].
__global__ __launch_bounds__(256) void qkv_gemm(
    const _Float16* __restrict__ A, const _Float16* __restrict__ B,
    _Float16* __restrict__ Qh, _Float16* __restrict__ Kh, _Float16* __restrict__ Vt) {
  int bx = blockIdx.x, by = blockIdx.y;
  const _Float16* Ab = A + (long long)by * 128 * 1024;
  const _Float16* Bb = B + (long long)bx * 128 * 1024;

  __shared__ _Float16 lA[128 * 32];
  __shared__ _Float16 lB[128 * 32];

  int tid = threadIdx.x;
  int r0 = tid >> 2;
  int c0 = (tid & 3) * 8;
  const _Float16* ga0 = Ab + (long long)r0 * 1024 + c0;
  const _Float16* ga1 = Ab + (long long)(r0 + 64) * 1024 + c0;
  const _Float16* gb0 = Bb + (long long)r0 * 1024 + c0;
  const _Float16* gb1 = Bb + (long long)(r0 + 64) * 1024 + c0;
  _Float16* la0 = lA + tid * 8;
  _Float16* la1 = lA + 2048 + tid * 8;
  _Float16* lb0 = lB + tid * 8;
  _Float16* lb1 = lB + 2048 + tid * 8;

  f32x4 acc[4][4] = {};
  int lane = tid & 63;
  int wv = tid >> 6;
  int wm = (wv & 1) * 64, wn = (wv >> 1) * 64;
  int l16 = lane & 15, quad = lane >> 4;
  const _Float16* raBase = lA + (wm + l16) * 32 + quad * 8;
  const _Float16* rbBase = lB + (wn + l16) * 32 + quad * 8;

  for (int kb = 0; kb < 1024; kb += 32) {
    __syncthreads();
    load16_lds(ga0, la0);
    load16_lds(ga1, la1);
    load16_lds(gb0, lb0);
    load16_lds(gb1, lb1);
    ga0 += 32; ga1 += 32; gb0 += 32; gb1 += 32;
    __syncthreads();
    f16x8 af[4], bfr[4];
    #pragma unroll
    for (int i = 0; i < 4; i++) af[i] = *(const f16x8*)(raBase + i * 512);
    #pragma unroll
    for (int j = 0; j < 4; j++) bfr[j] = *(const f16x8*)(rbBase + j * 512);
    #pragma unroll
    for (int i = 0; i < 4; i++)
      #pragma unroll
      for (int j = 0; j < 4; j++)
        acc[i][j] = __builtin_amdgcn_mfma_f32_16x16x32_f16(af[i], bfr[j], acc[i][j], 0, 0, 0);
  }

  int m0 = by * 128 + wm + quad * 4;
  int n0 = bx * 128 + wn + l16;

  if (bx < 16) {
    _Float16* C = (bx < 8) ? Qh : Kh;
    int nr = n0 & 1023;
    #pragma unroll
    for (int i = 0; i < 4; i++)
      #pragma unroll
      for (int j = 0; j < 4; j++)
        #pragma unroll
        for (int r = 0; r < 4; r++)
          C[(long long)(m0 + i * 16 + r) * 1024 + (nr + j * 16)] = (_Float16)acc[i][j][r];
  } else {
    int d0 = n0 - 2048;
    #pragma unroll
    for (int i = 0; i < 4; i++) {
      long long mm = m0 + i * 16;
      long long b = mm >> 11;
      long long s = mm & 2047;
      #pragma unroll
      for (int j = 0; j < 4; j++) {
        f16x4 pk;
        #pragma unroll
        for (int r = 0; r < 4; r++) pk[r] = (_Float16)acc[i][j][r];
        *(f16x4*)(Vt + (b << 21) + (long long)(d0 + j * 16) * 2048 + s) = pk;
      }
    }
  }
}

// ---------------- split-K PV GEMM ----------------
// O = P @ Vt^T, K split at 1024. grid (8, 24, 4).
// cy<8: by=cy, chunk 0 -> ROW COMPLETE (k<=1024) -> write Oh fp16 directly.
// cy>=8: by=8+(cy-8)/2, chunk=(cy-8)%2 -> fp32 partials P0/P1, reduced later.
__global__ __launch_bounds__(256) void pv_splitk(
    const _Float16* __restrict__ P,   // Sb upper halves: lda=4096, batch 8388608
    const _Float16* __restrict__ Vt,  // [b][1024][2048]
    float* __restrict__ P0, float* __restrict__ P1,
    _Float16* __restrict__ Oh) {
  int bx = blockIdx.x, cy = blockIdx.y, bz = blockIdx.z;
  int by, c;
  if (cy < 8) { by = cy; c = 0; }
  else { int q = cy - 8; by = 8 + (q >> 1); c = q & 1; }
  int kmax = (by + 1) * 128;
  int k0 = c * 1024;
  int klen = min(kmax, k0 + 1024) - k0;

  const _Float16* Ab = P + (long long)bz * 8388608LL + (long long)by * 128 * 4096 + k0;
  const _Float16* Bb = Vt + (long long)bz * 2097152LL + (long long)bx * 128 * 2048 + k0;

  __shared__ _Float16 lA[128 * 32];
  __shared__ _Float16 lB[128 * 32];

  int tid = threadIdx.x;
  int r0 = tid >> 2;
  int c0 = (tid & 3) * 8;
  const _Float16* ga0 = Ab + (long long)r0 * 4096 + c0;
  const _Float16* ga1 = Ab + (long long)(r0 + 64) * 4096 + c0;
  const _Float16* gb0 = Bb + (long long)r0 * 2048 + c0;
  const _Float16* gb1 = Bb + (long long)(r0 + 64) * 2048 + c0;
  _Float16* la0 = lA + tid * 8;
  _Float16* la1 = lA + 2048 + tid * 8;
  _Float16* lb0 = lB + tid * 8;
  _Float16* lb1 = lB + 2048 + tid * 8;

  f32x4 acc[4][4] = {};
  int lane = tid & 63;
  int wv = tid >> 6;
  int wm = (wv & 1) * 64, wn = (wv >> 1) * 64;
  int l16 = lane & 15, quad = lane >> 4;
  const _Float16* raBase = lA + (wm + l16) * 32 + quad * 8;
  const _Float16* rbBase = lB + (wn + l16) * 32 + quad * 8;

  for (int kb = 0; kb < klen; kb += 32) {
    __syncthreads();
    load16_lds(ga0, la0);
    load16_lds(ga1, la1);
    load16_lds(gb0, lb0);
    load16_lds(gb1, lb1);
    ga0 += 32; ga1 += 32; gb0 += 32; gb1 += 32;
    __syncthreads();
    f16x8 af[4], bfr[4];
    #pragma unroll
    for (int i = 0; i < 4; i++) af[i] = *(const f16x8*)(raBase + i * 512);
    #pragma unroll
    for (int j = 0; j < 4; j++) bfr[j] = *(const f16x8*)(rbBase + j * 512);
    #pragma unroll
    for (int i = 0; i < 4; i++)
      #pragma unroll
      for (int j = 0; j < 4; j++)
        acc[i][j] = __builtin_amdgcn_mfma_f32_16x16x32_f16(af[i], bfr[j], acc[i][j], 0, 0, 0);
  }

  int m0 = by * 128 + wm + quad * 4;
  int n0 = bx * 128 + wn + l16;

  if (c == 0 && by < 8) {
    _Float16* C = Oh + (long long)bz * 2097152LL;
    #pragma unroll
    for (int i = 0; i < 4; i++)
      #pragma unroll
      for (int j = 0; j < 4; j++)
        #pragma unroll
        for (int r = 0; r < 4; r++)
          C[(long long)(m0 + i * 16 + r) * 1024 + (n0 + j * 16)] = (_Float16)acc[i][j][r];
  } else if (c == 0) {
    float* C = P0 + (long long)bz * 2097152LL;
    #pragma unroll
    for (int i = 0; i < 4; i++)
      #pragma unroll
      for (int j = 0; j < 4; j++)
        #pragma unroll
        for (int r = 0; r < 4; r++)
          C[(long long)(m0 + i * 16 + r) * 1024 + (n0 + j * 16)] = acc[i][j][r];
  } else {
    float* C = P1 + (long long)bz * 1048576LL;
    int mr = m0 - 1024;
    #pragma unroll
    for (int i = 0; i < 4; i++)
      #pragma unroll
      for (int j = 0; j < 4; j++)
        #pragma unroll
        for (int r = 0; r < 4; r++)
          C[(long long)(mr + i * 16 + r) * 1024 + (n0 + j * 16)] = acc[i][j][r];
  }
}

// ---------------- PV reduce, upper 1024 rows only ----------------
// Oh[bz][1024+r][:] = f16(P0[bz][1024+r][:] + P1[bz][r][:])
__global__ __launch_bounds__(256) void pv_reduce(const float* __restrict__ P0,
                                                 const float* __restrict__ P1,
                                                 _Float16* __restrict__ Oh) {
  int i = blockIdx.x * 256 + threadIdx.x;  // float4 index over 4*1024*1024 floats
  if (i >= 1048576) return;
  int f4 = i;                 // float4 granularity
  int bz = f4 >> 18;          // 262144 float4 per batch
  int loc = f4 & 262143;      // (r*1024 + col)/4
  long long p0i = (long long)bz * 524288 + 262144 + loc;  // (bz*2097152 + 1048576)/4 + loc
  float4 v = ((const float4*)P0)[p0i];
  float4 w = ((const float4*)P1)[f4];
  v.x += w.x; v.y += w.y; v.z += w.z; v.w += w.w;
  f16x4 o;
  o[0] = (_Float16)v.x; o[1] = (_Float16)v.y; o[2] = (_Float16)v.z; o[3] = (_Float16)v.w;
  ((f16x4*)Oh)[p0i] = o;
}

// ---------------- workspace layout (bytes) ----------------
// xh  : 0          16,777,216   x fp16              -> P1 (16 MB) during PV
// Wcat: 16777216    6,291,456   Wq|Wk|Wv fp16 [3072][1024]
// Woh : 23068672    2,097,152
// Qh  : 25165824   16,777,216   -> P0 first half during PV
// Kh  : 41943040   16,777,216   -> P0 second half during PV
// Vt  : 58720256   16,777,216   [b][d=1024][s=2048]
// Oh  : 75497472   16,777,216
// Sb  : 92274688   67,108,864   fp32 scores; fp16 P in upper 4KB of each row
// total: 159,383,552

extern "C" void kernel_launch(void* const* d_in, const int* in_sizes, int n_in,
                              void* d_out, int out_size, void* d_ws, size_t ws_size,
                              hipStream_t stream) {
  const float* x  = (const float*)d_in[0];
  const float* Wq = (const float*)d_in[1];
  const float* Wk = (const float*)d_in[2];
  const float* Wv = (const float*)d_in[3];
  const float* Wo = (const float*)d_in[4];
  const float* bO = (const float*)d_in[5];

  char* ws = (char*)d_ws;
  _Float16* xh   = (_Float16*)(ws + 0);
  _Float16* Wcat = (_Float16*)(ws + 16777216);
  _Float16* Woh  = (_Float16*)(ws + 23068672);
  _Float16* Qh   = (_Float16*)(ws + 25165824);
  _Float16* Kh   = (_Float16*)(ws + 41943040);
  _Float16* Vt   = (_Float16*)(ws + 58720256);
  _Float16* Oh   = (_Float16*)(ws + 75497472);
  float*    Sb   = (float*)   (ws + 92274688);
  float*    P0   = (float*)   (ws + 25165824);  // aliases Qh+Kh (dead by PV)
  float*    P1   = (float*)   (ws + 0);         // aliases xh (dead by PV)

  dim3 blk(256);

  // all fp32->fp16 input conversions in one launch
  cvt_all<<<12288, blk, 0, stream>>>(x, Wq, Wk, Wv, Wo, xh, Wcat, Woh);

  // fused Q/K/V projection (V stored transposed)
  qkv_gemm<<<dim3(24, 64, 1), blk, 0, stream>>>(xh, Wcat, Qh, Kh, Vt);

  // S = Q @ K^T per batch (fp32), lower-triangular 128-tiles only
  gemm_bt<2, true><<<dim3(16, 16, 4), blk, 0, stream>>>(
      Qh, Kh, Sb, nullptr, 1024, 1024, 1024, 2048,
      2097152LL, 2097152LL, 4194304LL);

  // causal softmax -> fp16 P in upper half of each score row
  softmax_causal<<<8192, blk, 0, stream>>>(Sb);

  // O = P @ Vt^T with split-K; k<=1024 tiles write Oh directly
  pv_splitk<<<dim3(8, 24, 4), blk, 0, stream>>>(
      (const _Float16*)Sb + 2048, Vt, P0, P1, Oh);
  pv_reduce<<<4096, blk, 0, stream>>>(P0, P1, Oh);

  // out = O @ Wo^T + b_O
  gemm_bt<3, false><<<dim3(8, 64, 1), blk, 0, stream>>>(
      Oh, Woh, (float*)d_out, bO, 1024, 1024, 1024, 1024, 0, 0, 0);
}

// Round 4
// 306.391 us; speedup vs baseline: 1.1108x; 1.1108x over previous
//
#include <hip/hip_runtime.h>
#include <cstdint>

typedef _Float16 f16x8 __attribute__((ext_vector_type(8)));
typedef _Float16 f16x4 __attribute__((ext_vector_type(4)));
typedef float    f32x4 __attribute__((ext_vector_type(4)));

#define AS1 __attribute__((address_space(1)))
#define AS3 __attribute__((address_space(3)))

__device__ __forceinline__ void load16_lds(const void* g, void* l) {
  __builtin_amdgcn_global_load_lds((AS1 void*)g, (AS3 void*)l, 16, 0, 0);
}

// ---------------- fused fp32 -> fp16 convert for all 5 inputs ----------------
__global__ __launch_bounds__(256) void cvt_all(
    const float* __restrict__ x, const float* __restrict__ wq,
    const float* __restrict__ wk, const float* __restrict__ wv,
    const float* __restrict__ wo,
    _Float16* __restrict__ xh, _Float16* __restrict__ wcat,
    _Float16* __restrict__ woh) {
  long long g = (long long)blockIdx.x * 256 + threadIdx.x;
  const float* in; _Float16* out; long long idx;
  if (g < 2097152)      { in = x;  out = xh;             idx = g; }
  else if (g < 2359296) { in = wq; out = wcat;           idx = g - 2097152; }
  else if (g < 2621440) { in = wk; out = wcat + 1048576; idx = g - 2359296; }
  else if (g < 2883584) { in = wv; out = wcat + 2097152; idx = g - 2621440; }
  else                  { in = wo; out = woh;            idx = g - 2883584; }
  float4 v = ((const float4*)in)[idx];
  f16x4 o;
  o[0] = (_Float16)v.x; o[1] = (_Float16)v.y; o[2] = (_Float16)v.z; o[3] = (_Float16)v.w;
  ((f16x4*)out)[idx] = o;
}

// ---------------- fused QKV projection ----------------
// A = xh [8192][1024], B = Wcat [3072][1024] (Wq|Wk|Wv rows).
// grid (24, 64): bx<8 -> Qh, bx<16 -> Kh, else Vt transposed [b][d][s].
__global__ __launch_bounds__(256) void qkv_gemm(
    const _Float16* __restrict__ A, const _Float16* __restrict__ B,
    _Float16* __restrict__ Qh, _Float16* __restrict__ Kh, _Float16* __restrict__ Vt) {
  int bx = blockIdx.x, by = blockIdx.y;
  const _Float16* Ab = A + (long long)by * 128 * 1024;
  const _Float16* Bb = B + (long long)bx * 128 * 1024;

  __shared__ _Float16 lA[128 * 32];
  __shared__ _Float16 lB[128 * 32];

  int tid = threadIdx.x;
  int r0 = tid >> 2;
  int c0 = (tid & 3) * 8;
  const _Float16* ga0 = Ab + (long long)r0 * 1024 + c0;
  const _Float16* ga1 = Ab + (long long)(r0 + 64) * 1024 + c0;
  const _Float16* gb0 = Bb + (long long)r0 * 1024 + c0;
  const _Float16* gb1 = Bb + (long long)(r0 + 64) * 1024 + c0;
  _Float16* la0 = lA + tid * 8;
  _Float16* la1 = lA + 2048 + tid * 8;
  _Float16* lb0 = lB + tid * 8;
  _Float16* lb1 = lB + 2048 + tid * 8;

  f32x4 acc[4][4] = {};
  int lane = tid & 63;
  int wv = tid >> 6;
  int wm = (wv & 1) * 64, wn = (wv >> 1) * 64;
  int l16 = lane & 15, quad = lane >> 4;
  const _Float16* raBase = lA + (wm + l16) * 32 + quad * 8;
  const _Float16* rbBase = lB + (wn + l16) * 32 + quad * 8;

  for (int kb = 0; kb < 1024; kb += 32) {
    __syncthreads();
    load16_lds(ga0, la0);
    load16_lds(ga1, la1);
    load16_lds(gb0, lb0);
    load16_lds(gb1, lb1);
    ga0 += 32; ga1 += 32; gb0 += 32; gb1 += 32;
    __syncthreads();
    f16x8 af[4], bfr[4];
    #pragma unroll
    for (int i = 0; i < 4; i++) af[i] = *(const f16x8*)(raBase + i * 512);
    #pragma unroll
    for (int j = 0; j < 4; j++) bfr[j] = *(const f16x8*)(rbBase + j * 512);
    #pragma unroll
    for (int i = 0; i < 4; i++)
      #pragma unroll
      for (int j = 0; j < 4; j++)
        acc[i][j] = __builtin_amdgcn_mfma_f32_16x16x32_f16(af[i], bfr[j], acc[i][j], 0, 0, 0);
  }

  int m0 = by * 128 + wm + quad * 4;
  int n0 = bx * 128 + wn + l16;

  if (bx < 16) {
    _Float16* C = (bx < 8) ? Qh : Kh;
    int nr = n0 & 1023;
    #pragma unroll
    for (int i = 0; i < 4; i++)
      #pragma unroll
      for (int j = 0; j < 4; j++)
        #pragma unroll
        for (int r = 0; r < 4; r++)
          C[(long long)(m0 + i * 16 + r) * 1024 + (nr + j * 16)] = (_Float16)acc[i][j][r];
  } else {
    int d0 = n0 - 2048;
    #pragma unroll
    for (int i = 0; i < 4; i++) {
      long long mm = m0 + i * 16;
      long long b = mm >> 11;
      long long s = mm & 2047;
      #pragma unroll
      for (int j = 0; j < 4; j++) {
        f16x4 pk;
        #pragma unroll
        for (int r = 0; r < 4; r++) pk[r] = (_Float16)acc[i][j][r];
        *(f16x4*)(Vt + (b << 21) + (long long)(d0 + j * 16) * 2048 + s) = pk;
      }
    }
  }
}

// ---------------- scores GEMM with fused softmax statistics ----------------
// S_tile = Q_tile @ K_tile^T (K=1024). Stores u = s - m_t as fp16 into
// S [bz][2048][2048], and per-tile per-row stats {m_t, l_t=sum exp(s-m_t)}
// into stats[bz][row][bx] (float2). Diagonal tile masks cols > row.
__global__ __launch_bounds__(256) void scores_gemm(
    const _Float16* __restrict__ Qh, const _Float16* __restrict__ Kh,
    _Float16* __restrict__ S, float2* __restrict__ stats) {
  int bx = blockIdx.x, by = blockIdx.y, bz = blockIdx.z;
  if (bx > by) return;
  const _Float16* Ab = Qh + (long long)bz * 2097152 + (long long)by * 128 * 1024;
  const _Float16* Bb = Kh + (long long)bz * 2097152 + (long long)bx * 128 * 1024;

  __shared__ _Float16 lA[128 * 32];
  __shared__ _Float16 lB[128 * 32];
  __shared__ float redM[128];
  __shared__ float redL[128];

  int tid = threadIdx.x;
  int r0 = tid >> 2;
  int c0 = (tid & 3) * 8;
  const _Float16* ga0 = Ab + (long long)r0 * 1024 + c0;
  const _Float16* ga1 = Ab + (long long)(r0 + 64) * 1024 + c0;
  const _Float16* gb0 = Bb + (long long)r0 * 1024 + c0;
  const _Float16* gb1 = Bb + (long long)(r0 + 64) * 1024 + c0;
  _Float16* la0 = lA + tid * 8;
  _Float16* la1 = lA + 2048 + tid * 8;
  _Float16* lb0 = lB + tid * 8;
  _Float16* lb1 = lB + 2048 + tid * 8;

  f32x4 acc[4][4] = {};
  int lane = tid & 63;
  int wv = tid >> 6;
  int wm = (wv & 1) * 64, wn = (wv >> 1) * 64;
  int l16 = lane & 15, quad = lane >> 4;
  const _Float16* raBase = lA + (wm + l16) * 32 + quad * 8;
  const _Float16* rbBase = lB + (wn + l16) * 32 + quad * 8;

  for (int kb = 0; kb < 1024; kb += 32) {
    __syncthreads();
    load16_lds(ga0, la0);
    load16_lds(ga1, la1);
    load16_lds(gb0, lb0);
    load16_lds(gb1, lb1);
    ga0 += 32; ga1 += 32; gb0 += 32; gb1 += 32;
    __syncthreads();
    f16x8 af[4], bfr[4];
    #pragma unroll
    for (int i = 0; i < 4; i++) af[i] = *(const f16x8*)(raBase + i * 512);
    #pragma unroll
    for (int j = 0; j < 4; j++) bfr[j] = *(const f16x8*)(rbBase + j * 512);
    #pragma unroll
    for (int i = 0; i < 4; i++)
      #pragma unroll
      for (int j = 0; j < 4; j++)
        acc[i][j] = __builtin_amdgcn_mfma_f32_16x16x32_f16(af[i], bfr[j], acc[i][j], 0, 0, 0);
  }

  // ---- epilogue: per-tile row max / sum-of-exp + u stores ----
  bool diag = (bx == by);
  int rloc0 = wm + quad * 4;   // + i*16 + r
  int cloc0 = wn + l16;        // + j*16

  // pass 1: row max over this wave's 64 cols (masked on diag tile)
  float mloc[4][4];
  #pragma unroll
  for (int i = 0; i < 4; i++)
    #pragma unroll
    for (int r = 0; r < 4; r++) {
      float mx = -3.0e38f;
      #pragma unroll
      for (int j = 0; j < 4; j++) {
        bool ok = !diag || (cloc0 + j * 16 <= rloc0 + i * 16 + r);
        float s = acc[i][j][r];
        mx = ok ? fmaxf(mx, s) : mx;
      }
      #pragma unroll
      for (int d = 1; d < 16; d <<= 1) mx = fmaxf(mx, __shfl_xor(mx, d));
      mloc[i][r] = mx;
    }
  __syncthreads();
  if (wn && (lane & 15) == 0) {
    #pragma unroll
    for (int i = 0; i < 4; i++)
      #pragma unroll
      for (int r = 0; r < 4; r++) redM[rloc0 + i * 16 + r] = mloc[i][r];
  }
  __syncthreads();
  if (!wn) {
    #pragma unroll
    for (int i = 0; i < 4; i++)
      #pragma unroll
      for (int r = 0; r < 4; r++)
        mloc[i][r] = fmaxf(mloc[i][r], redM[rloc0 + i * 16 + r]);
  }
  __syncthreads();
  if (!wn && (lane & 15) == 0) {
    #pragma unroll
    for (int i = 0; i < 4; i++)
      #pragma unroll
      for (int r = 0; r < 4; r++) redM[rloc0 + i * 16 + r] = mloc[i][r];
  }
  __syncthreads();
  float mfin[4][4];
  #pragma unroll
  for (int i = 0; i < 4; i++)
    #pragma unroll
    for (int r = 0; r < 4; r++) mfin[i][r] = redM[rloc0 + i * 16 + r];

  // pass 2: sum of exp(s - m_t) over valid cols
  float lloc[4][4];
  #pragma unroll
  for (int i = 0; i < 4; i++)
    #pragma unroll
    for (int r = 0; r < 4; r++) {
      float sum = 0.f;
      #pragma unroll
      for (int j = 0; j < 4; j++) {
        bool ok = !diag || (cloc0 + j * 16 <= rloc0 + i * 16 + r);
        float e = __expf(acc[i][j][r] - mfin[i][r]);
        sum += ok ? e : 0.f;
      }
      #pragma unroll
      for (int d = 1; d < 16; d <<= 1) sum += __shfl_xor(sum, d);
      lloc[i][r] = sum;
    }
  if (wn && (lane & 15) == 0) {
    #pragma unroll
    for (int i = 0; i < 4; i++)
      #pragma unroll
      for (int r = 0; r < 4; r++) redL[rloc0 + i * 16 + r] = lloc[i][r];
  }
  __syncthreads();
  if (!wn && (lane & 15) == 0) {
    #pragma unroll
    for (int i = 0; i < 4; i++)
      #pragma unroll
      for (int r = 0; r < 4; r++) {
        int rl = rloc0 + i * 16 + r;
        float lt = lloc[i][r] + redL[rl];
        stats[((long long)bz * 2048 + by * 128 + rl) * 16 + bx] =
            make_float2(mfin[i][r], lt);
      }
  }

  // store u = s - m_t (fp16)
  _Float16* Sb = S + (long long)bz * 4194304;
  int m0 = by * 128 + rloc0;
  int n0 = bx * 128 + cloc0;
  #pragma unroll
  for (int i = 0; i < 4; i++)
    #pragma unroll
    for (int j = 0; j < 4; j++)
      #pragma unroll
      for (int r = 0; r < 4; r++)
        Sb[(long long)(m0 + i * 16 + r) * 2048 + (n0 + j * 16)] =
            (_Float16)(acc[i][j][r] - mfin[i][r]);
}

// ---------------- normalize: u -> p in place ----------------
// One block per row. Combines the row's <=16 tile stats (no data scan), then
// p = exp(u + (m_t - m)) / l for col<=row, 0 for col in (row, Lp).
__global__ __launch_bounds__(256) void normalize_p(_Float16* __restrict__ S,
                                                   const float2* __restrict__ stats) {
  int g = blockIdx.x;
  int bz = g >> 11, row = g & 2047;
  int nt = (row >> 7) + 1;
  _Float16* srow = S + ((long long)bz * 2048 + row) * 2048;
  const float2* st = stats + ((long long)bz * 2048 + row) * 16;
  __shared__ float sh_invl;
  __shared__ float shd[16];
  int t = threadIdx.x;
  if (t < 16) {
    float2 p = (t < nt) ? st[t] : make_float2(-3.0e38f, 0.f);
    float m = p.x;
    #pragma unroll
    for (int d = 1; d < 16; d <<= 1) m = fmaxf(m, __shfl_xor(m, d));
    float term = p.y * __expf(p.x - m);
    #pragma unroll
    for (int d = 1; d < 16; d <<= 1) term += __shfl_xor(term, d);
    shd[t] = p.x - m;
    if (t == 0) sh_invl = 1.0f / term;
  }
  __syncthreads();
  float invl = sh_invl;
  int Lp = nt << 7;
  for (int c = t; (c << 3) < Lp; c += 256) {
    float dt = shd[c >> 4];
    f16x8 v = ((f16x8*)srow)[c];
    f16x8 o;
    int col0 = c << 3;
    #pragma unroll
    for (int e = 0; e < 8; e++) {
      float u = (float)v[e];
      float pe = __expf(u + dt) * invl;
      o[e] = (col0 + e <= row) ? (_Float16)pe : (_Float16)0.f;
    }
    ((f16x8*)srow)[c] = o;
  }
}

// ---------------- split-K PV GEMM ----------------
// O = P @ Vt^T, P = S fp16 [bz][2048][2048]. K split at 1024. grid (8, 24, 4).
__global__ __launch_bounds__(256) void pv_splitk(
    const _Float16* __restrict__ P,
    const _Float16* __restrict__ Vt,  // [b][1024][2048]
    float* __restrict__ P0, float* __restrict__ P1,
    _Float16* __restrict__ Oh) {
  int bx = blockIdx.x, cy = blockIdx.y, bz = blockIdx.z;
  int by, c;
  if (cy < 8) { by = cy; c = 0; }
  else { int q = cy - 8; by = 8 + (q >> 1); c = q & 1; }
  int kmax = (by + 1) * 128;
  int k0 = c * 1024;
  int klen = min(kmax, k0 + 1024) - k0;

  const _Float16* Ab = P + (long long)bz * 4194304LL + (long long)by * 128 * 2048 + k0;
  const _Float16* Bb = Vt + (long long)bz * 2097152LL + (long long)bx * 128 * 2048 + k0;

  __shared__ _Float16 lA[128 * 32];
  __shared__ _Float16 lB[128 * 32];

  int tid = threadIdx.x;
  int r0 = tid >> 2;
  int c0 = (tid & 3) * 8;
  const _Float16* ga0 = Ab + (long long)r0 * 2048 + c0;
  const _Float16* ga1 = Ab + (long long)(r0 + 64) * 2048 + c0;
  const _Float16* gb0 = Bb + (long long)r0 * 2048 + c0;
  const _Float16* gb1 = Bb + (long long)(r0 + 64) * 2048 + c0;
  _Float16* la0 = lA + tid * 8;
  _Float16* la1 = lA + 2048 + tid * 8;
  _Float16* lb0 = lB + tid * 8;
  _Float16* lb1 = lB + 2048 + tid * 8;

  f32x4 acc[4][4] = {};
  int lane = tid & 63;
  int wv = tid >> 6;
  int wm = (wv & 1) * 64, wn = (wv >> 1) * 64;
  int l16 = lane & 15, quad = lane >> 4;
  const _Float16* raBase = lA + (wm + l16) * 32 + quad * 8;
  const _Float16* rbBase = lB + (wn + l16) * 32 + quad * 8;

  for (int kb = 0; kb < klen; kb += 32) {
    __syncthreads();
    load16_lds(ga0, la0);
    load16_lds(ga1, la1);
    load16_lds(gb0, lb0);
    load16_lds(gb1, lb1);
    ga0 += 32; ga1 += 32; gb0 += 32; gb1 += 32;
    __syncthreads();
    f16x8 af[4], bfr[4];
    #pragma unroll
    for (int i = 0; i < 4; i++) af[i] = *(const f16x8*)(raBase + i * 512);
    #pragma unroll
    for (int j = 0; j < 4; j++) bfr[j] = *(const f16x8*)(rbBase + j * 512);
    #pragma unroll
    for (int i = 0; i < 4; i++)
      #pragma unroll
      for (int j = 0; j < 4; j++)
        acc[i][j] = __builtin_amdgcn_mfma_f32_16x16x32_f16(af[i], bfr[j], acc[i][j], 0, 0, 0);
  }

  int m0 = by * 128 + wm + quad * 4;
  int n0 = bx * 128 + wn + l16;

  if (c == 0 && by < 8) {
    _Float16* C = Oh + (long long)bz * 2097152LL;
    #pragma unroll
    for (int i = 0; i < 4; i++)
      #pragma unroll
      for (int j = 0; j < 4; j++)
        #pragma unroll
        for (int r = 0; r < 4; r++)
          C[(long long)(m0 + i * 16 + r) * 1024 + (n0 + j * 16)] = (_Float16)acc[i][j][r];
  } else if (c == 0) {
    float* C = P0 + (long long)bz * 2097152LL;
    #pragma unroll
    for (int i = 0; i < 4; i++)
      #pragma unroll
      for (int j = 0; j < 4; j++)
        #pragma unroll
        for (int r = 0; r < 4; r++)
          C[(long long)(m0 + i * 16 + r) * 1024 + (n0 + j * 16)] = acc[i][j][r];
  } else {
    float* C = P1 + (long long)bz * 1048576LL;
    int mr = m0 - 1024;
    #pragma unroll
    for (int i = 0; i < 4; i++)
      #pragma unroll
      for (int j = 0; j < 4; j++)
        #pragma unroll
        for (int r = 0; r < 4; r++)
          C[(long long)(mr + i * 16 + r) * 1024 + (n0 + j * 16)] = acc[i][j][r];
  }
}

// ---------------- PV reduce, upper 1024 rows only ----------------
__global__ __launch_bounds__(256) void pv_reduce(const float* __restrict__ P0,
                                                 const float* __restrict__ P1,
                                                 _Float16* __restrict__ Oh) {
  int i = blockIdx.x * 256 + threadIdx.x;
  if (i >= 1048576) return;
  int f4 = i;
  int bz = f4 >> 18;
  int loc = f4 & 262143;
  long long p0i = (long long)bz * 524288 + 262144 + loc;
  float4 v = ((const float4*)P0)[p0i];
  float4 w = ((const float4*)P1)[f4];
  v.x += w.x; v.y += w.y; v.z += w.z; v.w += w.w;
  f16x4 o;
  o[0] = (_Float16)v.x; o[1] = (_Float16)v.y; o[2] = (_Float16)v.z; o[3] = (_Float16)v.w;
  ((f16x4*)Oh)[p0i] = o;
}

// ---------------- output projection GEMM (+bias, fp32 out) ----------------
__global__ __launch_bounds__(256) void oproj_gemm(
    const _Float16* __restrict__ A, const _Float16* __restrict__ B,
    float* __restrict__ C, const float* __restrict__ bias) {
  int bx = blockIdx.x, by = blockIdx.y;
  const _Float16* Ab = A + (long long)by * 128 * 1024;
  const _Float16* Bb = B + (long long)bx * 128 * 1024;

  __shared__ _Float16 lA[128 * 32];
  __shared__ _Float16 lB[128 * 32];

  int tid = threadIdx.x;
  int r0 = tid >> 2;
  int c0 = (tid & 3) * 8;
  const _Float16* ga0 = Ab + (long long)r0 * 1024 + c0;
  const _Float16* ga1 = Ab + (long long)(r0 + 64) * 1024 + c0;
  const _Float16* gb0 = Bb + (long long)r0 * 1024 + c0;
  const _Float16* gb1 = Bb + (long long)(r0 + 64) * 1024 + c0;
  _Float16* la0 = lA + tid * 8;
  _Float16* la1 = lA + 2048 + tid * 8;
  _Float16* lb0 = lB + tid * 8;
  _Float16* lb1 = lB + 2048 + tid * 8;

  f32x4 acc[4][4] = {};
  int lane = tid & 63;
  int wv = tid >> 6;
  int wm = (wv & 1) * 64, wn = (wv >> 1) * 64;
  int l16 = lane & 15, quad = lane >> 4;
  const _Float16* raBase = lA + (wm + l16) * 32 + quad * 8;
  const _Float16* rbBase = lB + (wn + l16) * 32 + quad * 8;

  for (int kb = 0; kb < 1024; kb += 32) {
    __syncthreads();
    load16_lds(ga0, la0);
    load16_lds(ga1, la1);
    load16_lds(gb0, lb0);
    load16_lds(gb1, lb1);
    ga0 += 32; ga1 += 32; gb0 += 32; gb1 += 32;
    __syncthreads();
    f16x8 af[4], bfr[4];
    #pragma unroll
    for (int i = 0; i < 4; i++) af[i] = *(const f16x8*)(raBase + i * 512);
    #pragma unroll
    for (int j = 0; j < 4; j++) bfr[j] = *(const f16x8*)(rbBase + j * 512);
    #pragma unroll
    for (int i = 0; i < 4; i++)
      #pragma unroll
      for (int j = 0; j < 4; j++)
        acc[i][j] = __builtin_amdgcn_mfma_f32_16x16x32_f16(af[i], bfr[j], acc[i][j], 0, 0, 0);
  }

  int m0 = by * 128 + wm + quad * 4;
  int n0 = bx * 128 + wn + l16;
  #pragma unroll
  for (int j = 0; j < 4; j++) {
    float bj = bias[n0 + j * 16];
    #pragma unroll
    for (int i = 0; i < 4; i++)
      #pragma unroll
      for (int r = 0; r < 4; r++)
        C[(long long)(m0 + i * 16 + r) * 1024 + (n0 + j * 16)] = acc[i][j][r] + bj;
  }
}

// ---------------- workspace layout (bytes) ----------------
// xh   : 0          16,777,216   -> P1 alias during PV
// Wcat : 16777216    6,291,456
// Woh  : 23068672    2,097,152
// Qh   : 25165824   16,777,216   -> P0 alias (with Kh) during PV
// Kh   : 41943040   16,777,216
// Vt   : 58720256   16,777,216
// Oh   : 75497472   16,777,216
// Sb   : 92274688   33,554,432   fp16 u/p [4][2048][2048]
// stats: 125829120   1,048,576   float2 [4][2048][16]
// total: 126,877,696

extern "C" void kernel_launch(void* const* d_in, const int* in_sizes, int n_in,
                              void* d_out, int out_size, void* d_ws, size_t ws_size,
                              hipStream_t stream) {
  const float* x  = (const float*)d_in[0];
  const float* Wq = (const float*)d_in[1];
  const float* Wk = (const float*)d_in[2];
  const float* Wv = (const float*)d_in[3];
  const float* Wo = (const float*)d_in[4];
  const float* bO = (const float*)d_in[5];

  char* ws = (char*)d_ws;
  _Float16* xh   = (_Float16*)(ws + 0);
  _Float16* Wcat = (_Float16*)(ws + 16777216);
  _Float16* Woh  = (_Float16*)(ws + 23068672);
  _Float16* Qh   = (_Float16*)(ws + 25165824);
  _Float16* Kh   = (_Float16*)(ws + 41943040);
  _Float16* Vt   = (_Float16*)(ws + 58720256);
  _Float16* Oh   = (_Float16*)(ws + 75497472);
  _Float16* Sb   = (_Float16*)(ws + 92274688);
  float2*   stats= (float2*)  (ws + 125829120);
  float*    P0   = (float*)   (ws + 25165824);  // aliases Qh+Kh (dead by PV)
  float*    P1   = (float*)   (ws + 0);         // aliases xh (dead by PV)

  dim3 blk(256);

  cvt_all<<<12288, blk, 0, stream>>>(x, Wq, Wk, Wv, Wo, xh, Wcat, Woh);

  qkv_gemm<<<dim3(24, 64, 1), blk, 0, stream>>>(xh, Wcat, Qh, Kh, Vt);

  // scores + fused softmax statistics (fp16 u output)
  scores_gemm<<<dim3(16, 16, 4), blk, 0, stream>>>(Qh, Kh, Sb, stats);

  // combine stats + normalize u -> p in place
  normalize_p<<<8192, blk, 0, stream>>>(Sb, stats);

  // O = P @ Vt^T with split-K
  pv_splitk<<<dim3(8, 24, 4), blk, 0, stream>>>(Sb, Vt, P0, P1, Oh);
  pv_reduce<<<4096, blk, 0, stream>>>(P0, P1, Oh);

  // out = O @ Wo^T + b_O
  oproj_gemm<<<dim3(8, 64, 1), blk, 0, stream>>>(Oh, Woh, (float*)d_out, bO);
}